// Round 18
// baseline (414.745 us; speedup 1.0000x reference)
//
#include <hip/hip_runtime.h>
#include <math.h>

#define IMGD 224
#define HW 50176      // 224*224
#define NK 100
#define NB 8
#define OUT_PER_B 76800   // 100*16*16*3 = 300*256
#define NCHUNK 131        // OpenBLAS k-blocking of 50176: 129x384, 320, 320

// R12/R14 lesson: per-block device-scope fences serialize ~1.2-1.7 us of L2
// writeback EACH on gfx950 -> never reduce across blocks inside a kernel.
// Kernel boundary is the cheap coherence point. This round: combine folded
// into the NEXT iter as a redundant per-block prologue (no fences).

static __device__ __forceinline__ float ratio_f32() {
  return (float)(10.0 / sqrt(224.0 * 224.0 / 100.0));
}

// distance op sequence — the single source of truth for bit-exactness
static __device__ __forceinline__ float dist5s(float f0, float f1, float f2,
                                               float f3, float f4, float fsq,
                                               float c0, float c1, float c2,
                                               float c3, float c4, float q) {
  float dot = __fmul_rn(f0, c0);
  dot = __fmaf_rn(f1, c1, dot);
  dot = __fmaf_rn(f2, c2, dot);
  dot = __fmaf_rn(f3, c3, dot);
  dot = __fmaf_rn(f4, c4, dot);
  return __fsub_rn(__fadd_rn(fsq, q), __fmul_rn(2.0f, dot));
}

static __device__ __forceinline__ float fsq5(float f0, float f1, float f2,
                                             float f3, float f4) {
  float s = __fmul_rn(f0, f0);
  s = __fadd_rn(s, __fmul_rn(f1, f1));
  s = __fadd_rn(s, __fmul_rn(f2, f2));
  s = __fadd_rn(s, __fmul_rn(f3, f3));
  s = __fadd_rn(s, __fmul_rn(f4, f4));
  return s;
}

// ---------- setup: blocks 0..15 build A; blocks 16..23 init centers+c2 ----------
__global__ void __launch_bounds__(256) setup_kernel(
    const float* __restrict__ x, float* __restrict__ A,
    float* __restrict__ centers, float* __restrict__ c2g) {
  int blk = blockIdx.x;
  int tid = threadIdx.x;
  if (blk < 16) {
    __shared__ float red[256];
    int p = blk;
    float tri = 0.0f;
    if (tid < IMGD) {
      float center = (p + 0.5f) * 14.0f - 0.5f;
      float xd = fabsf(center - (float)tid) / 14.0f;
      tri = fmaxf(0.0f, 1.0f - xd);
    }
    red[tid] = tri;
    __syncthreads();
    for (int s = 128; s > 0; s >>= 1) {
      if (tid < s) red[tid] += red[tid + s];
      __syncthreads();
    }
    float Z = red[0];
    if (tid < IMGD) A[p * IMGD + tid] = tri / Z;
  } else {
    int b = blk - 16;
    int k = tid;
    if (k >= NK) return;
    int gy = k / 10, gx = k % 10;
    int cy = (int)((gy + 0.5) * 224.0 / 10.0);  // trunc like .astype(int32)
    int cx = (int)((gx + 0.5) * 224.0 / 10.0);
    int i = cy * IMGD + cx;
    const float ratio = ratio_f32();
    float c0 = x[((size_t)b * 3 + 0) * HW + i];
    float c1 = x[((size_t)b * 3 + 1) * HW + i];
    float c2 = x[((size_t)b * 3 + 2) * HW + i];
    float c3 = __fmul_rn((float)cy, ratio);
    float c4 = __fmul_rn((float)cx, ratio);
    float* c = centers + ((size_t)b * NK + k) * 5;
    c[0] = c0; c[1] = c1; c[2] = c2; c[3] = c3; c[4] = c4;
    float s = __fmul_rn(c0, c0);
    s = __fadd_rn(s, __fmul_rn(c1, c1));
    s = __fadd_rn(s, __fmul_rn(c2, c2));
    s = __fadd_rn(s, __fmul_rn(c3, c3));
    s = __fadd_rn(s, __fmul_rn(c4, c4));
    c2g[(size_t)b * NK + k] = s;
  }
}

// ---------- iter: [redundant combine of prev partials] + assign + partial ----------
// flag==0: centers from global (first iteration). flag==1: each block combines
// prev-iteration partials itself — spatial chains for all 100 k (pruning needs
// them), color chains only for its candidate union; block.x==0 combines all
// and persists centers to centersOut (ping-pong, read next iter for the
// cnt==0 carryover). All chain/divide/c2 op orders byte-identical to the old
// combine kernel => centers bit-equal => labels bit-equal.
__global__ void __launch_bounds__(128, 4) iter_kernel(
    const float* __restrict__ x, const float* __restrict__ centersIn,
    const float* __restrict__ c2gIn, const float* __restrict__ prevC,
    const float* __restrict__ spatIn, const float* __restrict__ colIn,
    float* __restrict__ spatOut, float* __restrict__ colOut,
    float* __restrict__ centersOut, int flag) {
  __shared__ float4 ck4[NK];
  __shared__ float2 ck2[NK];
  __shared__ unsigned int mask[NK * 12];
  __shared__ unsigned short ppk[NK * 12];
  __shared__ float4 cval4[384];
  __shared__ float  cvalf[384];
  __shared__ int cnt[128];
  __shared__ int offx[128];
  __shared__ int wtot;
  __shared__ float ubpart[12][10];
  __shared__ float ubg[12];
  __shared__ unsigned int candm[12][4];
  __shared__ unsigned char clist[12][104];
  __shared__ int clen[12];
  __shared__ float sspat[300];
  __shared__ float colsum[300];
  __shared__ unsigned int unionm[4];
  __shared__ unsigned char ulist[NK];
  __shared__ int uLen;
  int c = blockIdx.x, b = blockIdx.y;
  int tid = threadIdx.x;
  int start = (c < 129) ? c * 384 : 49536 + (c - 129) * 320;
  int len   = (c < 129) ? c == 130 ? 320 : 384 : 320;   // c<129 -> 384
  len = (c < 129) ? 384 : 320;

  const float ratio = ratio_f32();
  for (int t = tid; t < NK * 12; t += 128) mask[t] = 0u;
  if (tid < 48) candm[tid >> 2][tid & 3] = 0u;
  if (tid < 4) unionm[tid] = 0u;

  // pixel loads early (no LDS dependence) — overlap with combine/pruning
  const float* x0 = x + (size_t)b * 3 * HW;
  float f0[3], f1[3], f2[3], f3[3], f4[3], fq[3];
  bool vld[3];
  for (int r = 0; r < 3; ++r) {
    int t = tid + r * 128;
    vld[r] = (t < len);
    int i = start + (vld[r] ? t : 0);
    int y = i / IMGD, xw = i - y * IMGD;
    f0[r] = x0[i]; f1[r] = x0[HW + i]; f2[r] = x0[2 * HW + i];
    f3[r] = __fmul_rn((float)y, ratio);
    f4[r] = __fmul_rn((float)xw, ratio);
    fq[r] = fsq5(f0[r], f1[r], f2[r], f3[r], f4[r]);
  }

  float p0r = 0.f, p1r = 0.f, p2r = 0.f, c3r = 0.f, c4r = 0.f;
  float cntr = 0.f, mr = 1.f;
  if (flag == 0) {
    const float* cb = centersIn + (size_t)b * NK * 5;
    const float* c2b = c2gIn + (size_t)b * NK;
    if (tid < NK) {
      ck4[tid] = make_float4(cb[tid*5+0], cb[tid*5+1], cb[tid*5+2], cb[tid*5+3]);
      ck2[tid] = make_float2(cb[tid*5+4], c2b[tid]);
    }
    __syncthreads();
  } else {
    // phase A: spatial+count chains, all 100 k (ascending chunk = ref order)
    for (int u = tid; u < 300; u += 128) {
      int k = u / 3, j = u - 3 * k;
      const float* bp = spatIn + ((size_t)(b * NK + k) * 3 + j) * NCHUNK;
      float s = bp[0];
      for (int cc = 1; cc < NCHUNK; ++cc) s = __fadd_rn(s, bp[cc]);
      sspat[u] = s;
    }
    __syncthreads();
    // phase B: spatial centers (+carryover from prevC for cnt==0)
    if (tid < NK) {
      cntr = sspat[tid * 3 + 2];
      const float* pc = prevC + ((size_t)b * NK + tid) * 5;
      p0r = pc[0]; p1r = pc[1]; p2r = pc[2];
      float p3 = pc[3], p4 = pc[4];
      mr = fmaxf(cntr, 1.0f);    // np.maximum(cnt,1.0): exact int in f32
      c3r = (cntr > 0.0f) ? __fdiv_rn(sspat[tid * 3 + 0], mr) : p3;
      c4r = (cntr > 0.0f) ? __fdiv_rn(sspat[tid * 3 + 1], mr) : p4;
      ck4[tid].w = c3r;
      ck2[tid].x = c4r;
    }
    __syncthreads();
  }

  // UB phase: thread (g,kb) scans 10 centers; group bounds in-register
  if (tid < 120) {
    int g = tid / 10, kb = tid - 10 * g;
    int i0 = start + g * 32, i1 = i0 + 31;
    int ymin = i0 / IMGD, ymax = i1 / IMGD;
    int cmin = (ymin == ymax) ? (i0 - ymin * IMGD) : 0;
    int cmax = (ymin == ymax) ? (i1 - ymax * IMGD) : (IMGD - 1);
    float f3mn = __fmul_rn((float)ymin, ratio);
    float f3mx = __fmul_rn((float)ymax, ratio);
    float f4mn = __fmul_rn((float)cmin, ratio);
    float f4mx = __fmul_rn((float)cmax, ratio);
    float mn = 3.4e38f;
    for (int k = kb * 10; k < kb * 10 + 10; ++k) {
      float c3 = ck4[k].w, c4 = ck2[k].x;
      float dy = fmaxf(fabsf(c3 - f3mn), fabsf(c3 - f3mx));
      float dx = fmaxf(fabsf(c4 - f4mn), fabsf(c4 - f4mx));
      mn = fminf(mn, dy * dy + dx * dx + 3.0f);
    }
    ubpart[g][kb] = mn;
  }
  __syncthreads();
  if (tid < 12) {
    float mn = ubpart[tid][0];
    for (int j = 1; j < 10; ++j) mn = fminf(mn, ubpart[tid][j]);
    ubg[tid] = mn + 1.0f;   // slack >> all f32 rounding at these magnitudes
  }
  __syncthreads();
  if (tid < 120) {
    int g = tid / 10, kb = tid - 10 * g;
    int i0 = start + g * 32, i1 = i0 + 31;
    int ymin = i0 / IMGD, ymax = i1 / IMGD;
    int cmin = (ymin == ymax) ? (i0 - ymin * IMGD) : 0;
    int cmax = (ymin == ymax) ? (i1 - ymax * IMGD) : (IMGD - 1);
    float f3mn = __fmul_rn((float)ymin, ratio);
    float f3mx = __fmul_rn((float)ymax, ratio);
    float f4mn = __fmul_rn((float)cmin, ratio);
    float f4mx = __fmul_rn((float)cmax, ratio);
    float lim = ubg[g];
    for (int k = kb * 10; k < kb * 10 + 10; ++k) {
      float c3 = ck4[k].w, c4 = ck2[k].x;
      float dy = fmaxf(0.0f, fmaxf(f3mn - c3, c3 - f3mx));
      float dx = fmaxf(0.0f, fmaxf(f4mn - c4, c4 - f4mx));
      if (dy * dy + dx * dx <= lim) {
        atomicOr(&candm[g][k >> 5], 1u << (k & 31));
        atomicOr(&unionm[k >> 5], 1u << (k & 31));
      }
    }
  }
  __syncthreads();
  // dense ascending-k candidate lists per group + block union list
  if (tid < 12) {
    int len2 = 0;
    for (int w = 0; w < 4; ++w) {
      unsigned int m = candm[tid][w];
      while (m) {
        int j = __ffs(m) - 1;
        m &= m - 1;
        clist[tid][len2++] = (unsigned char)(w * 32 + j);
      }
    }
    clen[tid] = len2;
  }
  if (blockIdx.x == 0) {
    if (tid < NK) ulist[tid] = (unsigned char)tid;  // block0 combines all k
    if (tid == 127) uLen = NK;
  } else if (tid == 127) {
    int len2 = 0;
    for (int w = 0; w < 4; ++w) {
      unsigned int m = unionm[w];
      while (m) {
        int j = __ffs(m) - 1;
        m &= m - 1;
        ulist[len2++] = (unsigned char)(w * 32 + j);
      }
    }
    uLen = len2;
  }
  __syncthreads();

  if (flag) {
    // phase D: color chains for the union candidates
    int total = uLen * 3;
    for (int idx = tid; idx < total; idx += 128) {
      int e = idx / 3, j = idx - 3 * e;
      int k = ulist[e];
      const float* bp = colIn + ((size_t)(b * NK + k) * 3 + j) * NCHUNK;
      float s = bp[0];
      for (int cc = 1; cc < NCHUNK; ++cc) s = __fadd_rn(s, bp[cc]);
      colsum[k * 3 + j] = s;
    }
    __syncthreads();
    // phase E: full centers + c2 for candidates; block0 persists to global
    if (tid < NK) {
      bool cand = (((unionm[tid >> 5] >> (tid & 31)) & 1u) != 0u) ||
                  (blockIdx.x == 0);
      if (cand) {
        float c0 = (cntr > 0.0f) ? __fdiv_rn(colsum[tid*3+0], mr) : p0r;
        float c1 = (cntr > 0.0f) ? __fdiv_rn(colsum[tid*3+1], mr) : p1r;
        float c2 = (cntr > 0.0f) ? __fdiv_rn(colsum[tid*3+2], mr) : p2r;
        // c2 = sum(centers*centers): rounded products, sequential adds
        float q = __fmul_rn(c0, c0);
        q = __fadd_rn(q, __fmul_rn(c1, c1));
        q = __fadd_rn(q, __fmul_rn(c2, c2));
        q = __fadd_rn(q, __fmul_rn(c3r, c3r));
        q = __fadd_rn(q, __fmul_rn(c4r, c4r));
        ck4[tid] = make_float4(c0, c1, c2, c3r);
        ck2[tid] = make_float2(c4r, q);
        if (blockIdx.x == 0) {
          float* oc = centersOut + ((size_t)b * NK + tid) * 5;
          oc[0] = c0; oc[1] = c1; oc[2] = c2; oc[3] = c3r; oc[4] = c4r;
        }
      }
    }
    __syncthreads();
  }

  // pruned distance loop: candidates ascending k (first-index ties safe)
  float best[3]; int bk[3];
  for (int r = 0; r < 3; ++r) {
    best[r] = 3.4e38f; bk[r] = 0;
    int t = tid + r * 128;
    int g = (t < 384) ? (t >> 5) : 0;
    int n = clen[g];
    for (int j = 0; j < n; ++j) {
      int k = clist[g][j];
      float4 a4 = ck4[k];
      float2 a2 = ck2[k];
      float d = dist5s(f0[r], f1[r], f2[r], f3[r], f4[r], fq[r],
                       a4.x, a4.y, a4.z, a4.w, a2.x, a2.y);
      if (d < best[r]) { best[r] = d; bk[r] = k; }
    }
  }
  for (int r = 0; r < 3; ++r) {
    int t = tid + r * 128;
    if (vld[r]) atomicOr(&mask[bk[r] * 12 + (t >> 5)], 1u << (t & 31));
  }
  __syncthreads();

  // per-k cumulative popcounts
  int myCnt = 0;
  if (tid < NK) {
    int s = 0;
    for (int g = 0; g < 12; ++g) {
      ppk[tid * 12 + g] = (unsigned short)s;
      s += __popc(mask[tid * 12 + g]);
    }
    myCnt = s;
  }
  cnt[tid] = myCnt;
  __syncthreads();

  // inclusive prefix over 128 counts: shfl per wave + cross-wave fixup
  int v = myCnt;
  for (int d = 1; d < 64; d <<= 1) {
    int u = __shfl_up(v, d, 64);
    if ((tid & 63) >= d) v += u;
  }
  if (tid == 63) wtot = v;
  __syncthreads();
  if (tid >= 64) v += wtot;
  offx[tid] = v;
  __syncthreads();

  // stable VALUE scatter
  for (int r = 0; r < 3; ++r) {
    int t = tid + r * 128;
    if (vld[r]) {
      int g = t >> 5, j = t & 31;
      unsigned int m = mask[bk[r] * 12 + g];
      int rank = ppk[bk[r] * 12 + g] + __popc(m & ((1u << j) - 1u));
      int pos = offx[bk[r]] - cnt[bk[r]] + rank;
      cval4[pos] = make_float4(f0[r], f1[r], f2[r], f3[r]);
      cvalf[pos] = f4[r];
    }
  }
  __syncthreads();

  // scan: thread k walks its consecutive compacted range (ascending t)
  if (tid < NK) {
    int n = cnt[tid];
    int base = offx[tid] - n;
    float s0 = 0.f, s1 = 0.f, s2 = 0.f, s3 = 0.f, s4 = 0.f, s5 = 0.f;
    for (int m = 0; m < n; ++m) {
      float4 vv = cval4[base + m];
      float ww = cvalf[base + m];
      s0 = __fadd_rn(s0, vv.x);
      s1 = __fadd_rn(s1, vv.y);
      s2 = __fadd_rn(s2, vv.z);
      s3 = __fadd_rn(s3, vv.w);
      s4 = __fadd_rn(s4, ww);
      s5 += 1.0f;
    }
    float* sp = spatOut + ((size_t)(b * NK + tid) * 3) * NCHUNK + c;
    sp[0 * NCHUNK] = s3; sp[1 * NCHUNK] = s4; sp[2 * NCHUNK] = s5;
    float* cp = colOut + ((size_t)(b * NK + tid) * 3) * NCHUNK + c;
    cp[0 * NCHUNK] = s0; cp[1 * NCHUNK] = s1; cp[2 * NCHUNK] = s2;
  }
}

// ---------- final combine: one block per (b,k) ----------
__global__ void __launch_bounds__(128) combine_update_kernel(
    const float* __restrict__ centersPrev, float* __restrict__ centersOut,
    const float* __restrict__ spatP, const float* __restrict__ colP,
    float* __restrict__ c2g) {
  __shared__ float st[786];
  __shared__ float sums[6];
  __shared__ float newc[5];
  int bk = blockIdx.x;                 // b*NK + k
  int tid = threadIdx.x;
  const float* colBase = colP + (size_t)bk * 3 * NCHUNK;
  const float* spatBase = spatP + (size_t)bk * 3 * NCHUNK;
  for (int t = tid; t < 393; t += 128) { st[t] = colBase[t]; st[393 + t] = spatBase[t]; }
  __syncthreads();
  if (tid < 6) {
    const float* row = (tid < 3) ? (st + tid * NCHUNK) : (st + 393 + (tid - 3) * NCHUNK);
    float s = row[0];                  // C = 0 + chunk0 (exact)
    for (int c = 1; c < NCHUNK; ++c) s = __fadd_rn(s, row[c]);
    sums[tid] = s;                     // 0..2 colors, 3 f3, 4 f4, 5 cnt
  }
  __syncthreads();
  float cntv = sums[5];
  if (tid < 5) {
    float v;
    if (cntv > 0.0f) {
      float m = fmaxf(cntv, 1.0f);
      v = __fdiv_rn(sums[tid < 3 ? tid : tid], (tid < 3) ? m : m);  // same m
      v = __fdiv_rn((tid < 3) ? sums[tid] : sums[tid], m);
      v = __fdiv_rn(sums[tid], m);     // sums index: 0,1,2 colors; 3,4 spatial
      centersOut[(size_t)bk * 5 + tid] = v;
    } else {
      v = centersPrev[(size_t)bk * 5 + tid];
      centersOut[(size_t)bk * 5 + tid] = v;
    }
    newc[tid] = v;
  }
  __syncthreads();
  if (tid == 0) {
    float t0 = __fmul_rn(newc[0], newc[0]);
    t0 = __fadd_rn(t0, __fmul_rn(newc[1], newc[1]));
    t0 = __fadd_rn(t0, __fmul_rn(newc[2], newc[2]));
    t0 = __fadd_rn(t0, __fmul_rn(newc[3], newc[3]));
    t0 = __fadd_rn(t0, __fmul_rn(newc[4], newc[4]));
    c2g[bk] = t0;
  }
}

// ---------- final full-image assignment: 2 px/thread, k-batched by 4 ----------
__global__ void __launch_bounds__(256) assign_kernel(
    const float* __restrict__ x, const float* __restrict__ centers,
    const float* __restrict__ c2g, int* __restrict__ labels) {
  __shared__ float4 ck4[NK];
  __shared__ float2 ck2[NK];
  int b = blockIdx.y;
  int tid = threadIdx.x;
  int base = blockIdx.x * 512;   // grid.x = 98 -> 98*512 = 50176 exact

  const float* cb = centers + (size_t)b * NK * 5;
  const float* c2b = c2g + (size_t)b * NK;
  for (int k = tid; k < NK; k += 256) {
    ck4[k] = make_float4(cb[k*5+0], cb[k*5+1], cb[k*5+2], cb[k*5+3]);
    ck2[k] = make_float2(cb[k*5+4], c2b[k]);
  }
  __syncthreads();

  const float* x0 = x + (size_t)b * 3 * HW;
  const float ratio = ratio_f32();
  float f0[2], f1[2], f2[2], f3[2], f4[2], fq[2];
  float best[2]; int bk[2];
  for (int r = 0; r < 2; ++r) {
    int i = base + r * 256 + tid;
    int y = i / IMGD, xw = i - y * IMGD;
    f0[r] = x0[i]; f1[r] = x0[HW + i]; f2[r] = x0[2 * HW + i];
    f3[r] = __fmul_rn((float)y, ratio);
    f4[r] = __fmul_rn((float)xw, ratio);
    fq[r] = fsq5(f0[r], f1[r], f2[r], f3[r], f4[r]);
    best[r] = 3.4e38f; bk[r] = 0;
  }
  for (int kb = 0; kb < NK; kb += 4) {
    float4 a4[4]; float2 a2[4];
    for (int kk = 0; kk < 4; ++kk) { a4[kk] = ck4[kb + kk]; a2[kk] = ck2[kb + kk]; }
    for (int kk = 0; kk < 4; ++kk) {
      for (int r = 0; r < 2; ++r) {
        float d = dist5s(f0[r], f1[r], f2[r], f3[r], f4[r], fq[r],
                         a4[kk].x, a4[kk].y, a4[kk].z, a4[kk].w, a2[kk].x, a2[kk].y);
        if (d < best[r]) { best[r] = d; bk[r] = kb + kk; }  // first-index wins
      }
    }
  }
  int* lb = labels + (size_t)b * HW;
  for (int r = 0; r < 2; ++r) lb[base + r * 256 + tid] = bk[r];
}

// ---------- embed: block = (b,p,q); LDS bins per (k,c); direct stores ----------
__global__ void __launch_bounds__(256) embed_kernel(
    const float* __restrict__ x, const int* __restrict__ labels,
    const float* __restrict__ A, float* __restrict__ out) {
  __shared__ float sk[NK * 3];
  int b = blockIdx.y;
  int p = blockIdx.x >> 4;
  int q = blockIdx.x & 15;
  int tid = threadIdx.x;
  for (int t = tid; t < NK * 3; t += 256) sk[t] = 0.0f;
  __syncthreads();

  int h0 = max(0, 14 * p - 7), h1 = min(IMGD - 1, 14 * p + 20);
  int w0 = max(0, 14 * q - 7), w1 = min(IMGD - 1, 14 * q + 20);
  int hl = h1 - h0 + 1, wl = w1 - w0 + 1;
  int n = hl * wl;

  const float* xb = x + (size_t)b * 3 * HW;
  const int* lb = labels + (size_t)b * HW;
  const float* Ap = A + p * IMGD;
  const float* Aq = A + q * IMGD;

  for (int idx = tid; idx < n; idx += 256) {
    int dh = idx / wl;
    int hh = h0 + dh;
    int ww = w0 + (idx - dh * wl);
    int i = hh * IMGD + ww;
    float wgt = Ap[hh] * Aq[ww];
    int k = lb[i];
    atomicAdd(&sk[k * 3 + 0], wgt * xb[i]);
    atomicAdd(&sk[k * 3 + 1], wgt * xb[HW + i]);
    atomicAdd(&sk[k * 3 + 2], wgt * xb[2 * HW + i]);
  }
  __syncthreads();

  float* outb = out + (size_t)b * OUT_PER_B;
  int base = p * 48 + q * 3;
  for (int t = tid; t < NK * 3; t += 256) {
    int k = t / 3, c = t - 3 * k;
    int f = k * 768 + base + c;           // flat [K,P,P,C] index
    outb[(f & 255) * 300 + (f >> 8)] = sk[t];  // view(B,300,256) + transpose
  }
}

extern "C" void kernel_launch(void* const* d_in, const int* in_sizes, int n_in,
                              void* d_out, int out_size, void* d_ws, size_t ws_size,
                              hipStream_t stream) {
  const float* x = (const float*)d_in[0];
  float* out = (float*)d_out;
  char* ws = (char*)d_ws;
  // ws layout:
  float* A        = (float*)(ws);               // 14336 B
  float* centersA = (float*)(ws + 16384);       // 16000 B
  float* centersB = (float*)(ws + 36864);       // 16000 B
  float* c2g      = (float*)(ws + 57344);       // 3200 B
  int*   labels   = (int*)(ws + 90112);         // 1605632 B
  // partials: spat/col, double-buffered; each 8*100*3*131*4 = 1257600 B
  float* PA_s = (float*)(ws + 1703936);
  float* PA_c = (float*)(ws + 2961536);
  float* PB_s = (float*)(ws + 4219136);
  float* PB_c = (float*)(ws + 5476736);

  setup_kernel<<<24, 256, 0, stream>>>(x, A, centersA, c2g);

  dim3 cgrid(NCHUNK, NB);         // 131 x 8
  // it0: centers from setup; writes PA
  iter_kernel<<<cgrid, 128, 0, stream>>>(x, centersA, c2g, centersA,
                                         PA_s, PA_c, PA_s, PA_c, centersB, 0);
  for (int i = 1; i < 10; ++i) {
    if (i & 1) {  // odd: in=PA prev=A -> out PB, persist B
      iter_kernel<<<cgrid, 128, 0, stream>>>(x, centersA, c2g, centersA,
                                             PA_s, PA_c, PB_s, PB_c, centersB, 1);
    } else {      // even: in=PB prev=B -> out PA, persist A
      iter_kernel<<<cgrid, 128, 0, stream>>>(x, centersB, c2g, centersB,
                                             PB_s, PB_c, PA_s, PA_c, centersA, 1);
    }
  }
  // it9 (odd) wrote PB + centersB; final combine: PB -> centersA (+c2g)
  combine_update_kernel<<<NB * NK, 128, 0, stream>>>(centersB, centersA,
                                                     PB_s, PB_c, c2g);
  dim3 agrid(98, NB);             // 98*512 = 50176 exact
  assign_kernel<<<agrid, 256, 0, stream>>>(x, centersA, c2g, labels);

  dim3 egrid(256, NB);            // (p*16+q) x b
  embed_kernel<<<egrid, 256, 0, stream>>>(x, labels, A, out);
}

// Round 19
// 298.496 us; speedup vs baseline: 1.3895x; 1.3895x over previous
//
#include <hip/hip_runtime.h>
#include <math.h>

#define IMGD 224
#define HW 50176      // 224*224
#define NK 100
#define NB 8
#define OUT_PER_B 76800   // 100*16*16*3 = 300*256
#define NCHUNK 131        // OpenBLAS k-blocking of 50176: 129x384, 320, 320
#define MSTR 13           // mask/ppk row stride (13 coprime 32: no bank conflicts)

// R12/R14/R18 lesson: cross-block reduction inside a kernel is unaffordable on
// gfx950 in ANY form (fence ~1.5us/block serialized; redundant recompute ~12us/
// iter of L2 traffic). The separate tiny combine dispatch is the optimum; the
// kernel boundary is the only cheap coherence point.

static __device__ __forceinline__ float ratio_f32() {
  return (float)(10.0 / sqrt(224.0 * 224.0 / 100.0));
}

// distance op sequence — the single source of truth for bit-exactness
static __device__ __forceinline__ float dist5s(float f0, float f1, float f2,
                                               float f3, float f4, float fsq,
                                               float c0, float c1, float c2,
                                               float c3, float c4, float q) {
  float dot = __fmul_rn(f0, c0);
  dot = __fmaf_rn(f1, c1, dot);
  dot = __fmaf_rn(f2, c2, dot);
  dot = __fmaf_rn(f3, c3, dot);
  dot = __fmaf_rn(f4, c4, dot);
  return __fsub_rn(__fadd_rn(fsq, q), __fmul_rn(2.0f, dot));
}

static __device__ __forceinline__ float fsq5(float f0, float f1, float f2,
                                             float f3, float f4) {
  float s = __fmul_rn(f0, f0);
  s = __fadd_rn(s, __fmul_rn(f1, f1));
  s = __fadd_rn(s, __fmul_rn(f2, f2));
  s = __fadd_rn(s, __fmul_rn(f3, f3));
  s = __fadd_rn(s, __fmul_rn(f4, f4));
  return s;
}

// ---------- fused assign+partial: 1 chunk per 128-thread block ----------
// flag==0: self-init centers in LDS (identical FP ops to the old setup kernel;
// block c==0 persists them for combine#1's cnt==0 carryover). flag==1: read
// centers/c2 from global (written by the previous combine dispatch).
// Pruning: UB = min_k(dy_max^2+dx_max^2+3), keep k iff dy_min^2+dx_min^2 <=
// UB+1.0 (slack >> f32 rounding) => argmin + ascending-k first-index ties
// bit-preserved. Compaction add chains ascending-pixel (bit-exact).
__global__ void __launch_bounds__(128, 4) iter_kernel(
    const float* __restrict__ x, float* __restrict__ centers,
    const float* __restrict__ c2g, float* __restrict__ partials, int flag) {
  __shared__ float4 ck4[NK];
  __shared__ float2 ck2[NK];
  __shared__ unsigned int mask[NK * MSTR];
  __shared__ unsigned short ppk[NK * MSTR];
  __shared__ float4 cval4[384];
  __shared__ float  cvalf[384];
  __shared__ int cnt[128];
  __shared__ int offx[128];
  __shared__ int wtot;
  __shared__ float ubpart[12][10];
  __shared__ float ubg[12];
  __shared__ unsigned int candm[12][4];
  __shared__ unsigned char clist[12][104];
  __shared__ int clen[12];
  int c = blockIdx.x, b = blockIdx.y;
  int tid = threadIdx.x;
  int start = (c < 129) ? c * 384 : 49536 + (c - 129) * 320;
  int len   = (c < 129) ? 384 : 320;

  const float ratio = ratio_f32();
  const float* x0 = x + (size_t)b * 3 * HW;
  if (flag == 0) {
    // self-init: same ops as the old setup kernel => identical center values
    if (tid < NK) {
      int gy = tid / 10, gx = tid - 10 * (tid / 10);
      int cy = (int)((gy + 0.5) * 224.0 / 10.0);  // trunc like .astype(int32)
      int cx = (int)((gx + 0.5) * 224.0 / 10.0);
      int i = cy * IMGD + cx;
      float c0 = x0[i], c1 = x0[HW + i], c2 = x0[2 * HW + i];
      float c3 = __fmul_rn((float)cy, ratio);
      float c4 = __fmul_rn((float)cx, ratio);
      float s = __fmul_rn(c0, c0);
      s = __fadd_rn(s, __fmul_rn(c1, c1));
      s = __fadd_rn(s, __fmul_rn(c2, c2));
      s = __fadd_rn(s, __fmul_rn(c3, c3));
      s = __fadd_rn(s, __fmul_rn(c4, c4));
      ck4[tid] = make_float4(c0, c1, c2, c3);
      ck2[tid] = make_float2(c4, s);
      if (c == 0) {   // persist for combine#1's cnt==0 carryover
        float* oc = centers + ((size_t)b * NK + tid) * 5;
        oc[0] = c0; oc[1] = c1; oc[2] = c2; oc[3] = c3; oc[4] = c4;
      }
    }
  } else {
    const float* cb = centers + (size_t)b * NK * 5;
    const float* c2b = c2g + (size_t)b * NK;
    if (tid < NK) {
      ck4[tid] = make_float4(cb[tid*5+0], cb[tid*5+1], cb[tid*5+2], cb[tid*5+3]);
      ck2[tid] = make_float2(cb[tid*5+4], c2b[tid]);
    }
  }
  for (int t = tid; t < NK * MSTR; t += 128) mask[t] = 0u;
  if (tid < 48) candm[tid >> 2][tid & 3] = 0u;

  // pixel loads early (no LDS dependence) — overlap with pruning phases
  float f0[3], f1[3], f2[3], f3[3], f4[3], fq[3];
  bool vld[3];
  for (int r = 0; r < 3; ++r) {
    int t = tid + r * 128;
    vld[r] = (t < len);
    int i = start + (vld[r] ? t : 0);
    int y = i / IMGD, xw = i - y * IMGD;
    f0[r] = x0[i]; f1[r] = x0[HW + i]; f2[r] = x0[2 * HW + i];
    f3[r] = __fmul_rn((float)y, ratio);
    f4[r] = __fmul_rn((float)xw, ratio);
    fq[r] = fsq5(f0[r], f1[r], f2[r], f3[r], f4[r]);
  }
  __syncthreads();

  // UB phase: thread (g,kb) scans 10 centers; group bounds in-register
  if (tid < 120) {
    int g = tid / 10, kb = tid - 10 * g;
    int i0 = start + g * 32, i1 = i0 + 31;
    int ymin = i0 / IMGD, ymax = i1 / IMGD;
    int cmin = (ymin == ymax) ? (i0 - ymin * IMGD) : 0;
    int cmax = (ymin == ymax) ? (i1 - ymax * IMGD) : (IMGD - 1);
    float f3mn = __fmul_rn((float)ymin, ratio);
    float f3mx = __fmul_rn((float)ymax, ratio);
    float f4mn = __fmul_rn((float)cmin, ratio);
    float f4mx = __fmul_rn((float)cmax, ratio);
    float mn = 3.4e38f;
    for (int k = kb * 10; k < kb * 10 + 10; ++k) {
      float c3 = ck4[k].w, c4 = ck2[k].x;
      float dy = fmaxf(fabsf(c3 - f3mn), fabsf(c3 - f3mx));
      float dx = fmaxf(fabsf(c4 - f4mn), fabsf(c4 - f4mx));
      mn = fminf(mn, dy * dy + dx * dx + 3.0f);
    }
    ubpart[g][kb] = mn;
  }
  __syncthreads();
  if (tid < 12) {
    float mn = ubpart[tid][0];
    for (int j = 1; j < 10; ++j) mn = fminf(mn, ubpart[tid][j]);
    ubg[tid] = mn + 1.0f;   // slack >> all f32 rounding at these magnitudes
  }
  __syncthreads();
  if (tid < 120) {
    int g = tid / 10, kb = tid - 10 * g;
    int i0 = start + g * 32, i1 = i0 + 31;
    int ymin = i0 / IMGD, ymax = i1 / IMGD;
    int cmin = (ymin == ymax) ? (i0 - ymin * IMGD) : 0;
    int cmax = (ymin == ymax) ? (i1 - ymax * IMGD) : (IMGD - 1);
    float f3mn = __fmul_rn((float)ymin, ratio);
    float f3mx = __fmul_rn((float)ymax, ratio);
    float f4mn = __fmul_rn((float)cmin, ratio);
    float f4mx = __fmul_rn((float)cmax, ratio);
    float lim = ubg[g];
    for (int k = kb * 10; k < kb * 10 + 10; ++k) {
      float c3 = ck4[k].w, c4 = ck2[k].x;
      float dy = fmaxf(0.0f, fmaxf(f3mn - c3, c3 - f3mx));
      float dx = fmaxf(0.0f, fmaxf(f4mn - c4, c4 - f4mx));
      if (dy * dy + dx * dx <= lim)
        atomicOr(&candm[g][k >> 5], 1u << (k & 31));
    }
  }
  __syncthreads();
  // dense ascending-k candidate lists
  if (tid < 12) {
    int len2 = 0;
    for (int w = 0; w < 4; ++w) {
      unsigned int m = candm[tid][w];
      while (m) {
        int j = __ffs(m) - 1;
        m &= m - 1;
        clist[tid][len2++] = (unsigned char)(w * 32 + j);
      }
    }
    clen[tid] = len2;
  }
  __syncthreads();

  // pruned distance loop: candidates ascending k (first-index ties safe)
  float best[3]; int bk[3];
  for (int r = 0; r < 3; ++r) {
    best[r] = 3.4e38f; bk[r] = 0;
    int t = tid + r * 128;
    int g = (t < 384) ? (t >> 5) : 0;
    int n = clen[g];
    for (int j = 0; j < n; ++j) {
      int k = clist[g][j];
      float4 a4 = ck4[k];
      float2 a2 = ck2[k];
      float d = dist5s(f0[r], f1[r], f2[r], f3[r], f4[r], fq[r],
                       a4.x, a4.y, a4.z, a4.w, a2.x, a2.y);
      if (d < best[r]) { best[r] = d; bk[r] = k; }
    }
  }
  for (int r = 0; r < 3; ++r) {
    int t = tid + r * 128;
    if (vld[r]) atomicOr(&mask[bk[r] * MSTR + (t >> 5)], 1u << (t & 31));
  }
  __syncthreads();

  // per-k cumulative popcounts (stride-13 rows: conflict-free)
  int myCnt = 0;
  if (tid < NK) {
    int s = 0;
    for (int g = 0; g < 12; ++g) {
      ppk[tid * MSTR + g] = (unsigned short)s;
      s += __popc(mask[tid * MSTR + g]);
    }
    myCnt = s;
  }
  cnt[tid] = myCnt;
  __syncthreads();

  // inclusive prefix over 128 counts: shfl per wave + cross-wave fixup
  int v = myCnt;
  for (int d = 1; d < 64; d <<= 1) {
    int u = __shfl_up(v, d, 64);
    if ((tid & 63) >= d) v += u;
  }
  if (tid == 63) wtot = v;
  __syncthreads();
  if (tid >= 64) v += wtot;
  offx[tid] = v;
  __syncthreads();

  // stable VALUE scatter: pos = (off[k]-cnt[k]) + rank_within_k(t)
  for (int r = 0; r < 3; ++r) {
    int t = tid + r * 128;
    if (vld[r]) {
      int g = t >> 5, j = t & 31;
      unsigned int m = mask[bk[r] * MSTR + g];
      int rank = ppk[bk[r] * MSTR + g] + __popc(m & ((1u << j) - 1u));
      int pos = offx[bk[r]] - cnt[bk[r]] + rank;
      cval4[pos] = make_float4(f0[r], f1[r], f2[r], f3[r]);
      cvalf[pos] = f4[r];
    }
  }
  __syncthreads();

  // scan: thread k walks its consecutive compacted range (ascending t)
  if (tid < NK) {
    int n = cnt[tid];
    int base = offx[tid] - n;
    float s0 = 0.f, s1 = 0.f, s2 = 0.f, s3 = 0.f, s4 = 0.f, s5 = 0.f;
    for (int m = 0; m < n; ++m) {
      float4 vv = cval4[base + m];
      float ww = cvalf[base + m];
      s0 = __fadd_rn(s0, vv.x);
      s1 = __fadd_rn(s1, vv.y);
      s2 = __fadd_rn(s2, vv.z);
      s3 = __fadd_rn(s3, vv.w);
      s4 = __fadd_rn(s4, ww);
      s5 += 1.0f;
    }
    // k-major layout [b][k][j][c]: combine reads contiguous
    float* pp = partials + ((size_t)(b * NK + tid) * 6) * NCHUNK + c;
    pp[0 * NCHUNK] = s0; pp[1 * NCHUNK] = s1; pp[2 * NCHUNK] = s2;
    pp[3 * NCHUNK] = s3; pp[4 * NCHUNK] = s4; pp[5 * NCHUNK] = s5;
  }
}

// ---------- combine: one block per (b,k); LDS-staged 131-chains ----------
__global__ void __launch_bounds__(128) combine_update_kernel(
    float* __restrict__ centers, const float* __restrict__ partials,
    float* __restrict__ c2g) {
  __shared__ float st[6 * NCHUNK];
  __shared__ float sums[6];
  __shared__ float newc[5];
  int bk = blockIdx.x;                 // b*NK + k
  int tid = threadIdx.x;
  const float* base = partials + (size_t)bk * 6 * NCHUNK;
  for (int t = tid; t < 6 * NCHUNK; t += 128) st[t] = base[t];
  __syncthreads();
  if (tid < 6) {
    const float* row = st + tid * NCHUNK;
    float s = row[0];                  // C = 0 + chunk0 (exact)
    for (int c = 1; c < NCHUNK; ++c) s = __fadd_rn(s, row[c]);
    sums[tid] = s;
  }
  __syncthreads();
  float cntv = sums[5];
  float* cc = centers + (size_t)bk * 5;
  if (tid < 5) {
    float v;
    if (cntv > 0.0f) {                 // where(cnt>0, new, centers)
      float m = fmaxf(cntv, 1.0f);     // np.maximum(cnt,1.0): exact int in f32
      v = __fdiv_rn(sums[tid], m);
      cc[tid] = v;
    } else {
      v = cc[tid];                     // unchanged center
    }
    newc[tid] = v;
  }
  __syncthreads();
  if (tid == 0) {
    // c2 = sum(centers*centers): rounded products, sequential adds
    float t0 = __fmul_rn(newc[0], newc[0]);
    t0 = __fadd_rn(t0, __fmul_rn(newc[1], newc[1]));
    t0 = __fadd_rn(t0, __fmul_rn(newc[2], newc[2]));
    t0 = __fadd_rn(t0, __fmul_rn(newc[3], newc[3]));
    t0 = __fadd_rn(t0, __fmul_rn(newc[4], newc[4]));
    c2g[bk] = t0;
  }
}

// ---------- embed (fused final assign): block = (b,p,q) ----------
// Computes its A rows locally (byte-identical tree-reduction for Z => A values
// bit-equal to the old setup kernel) and its window pixels' labels itself via
// the window-box pruning bound (provably exact, ascending-k candidates =>
// labels bit-identical to the full argmin). LDS bins, direct stores.
__global__ void __launch_bounds__(256) embed_kernel(
    const float* __restrict__ x, const float* __restrict__ centers,
    const float* __restrict__ c2g, float* __restrict__ out) {
  __shared__ float red[256];
  __shared__ float Apv[28];
  __shared__ float Aqv[28];
  __shared__ float4 ck4[NK];
  __shared__ float2 ck2[NK];
  __shared__ float sk[NK * 3];
  __shared__ float ubk[128];
  __shared__ unsigned int candm[4];
  __shared__ unsigned char clist[NK];
  __shared__ int clen;
  int b = blockIdx.y;
  int p = blockIdx.x >> 4;
  int q = blockIdx.x & 15;
  int tid = threadIdx.x;

  // A row p: tri + tree-reduced Z (identical op order to old build_A)
  float cp = (p + 0.5f) * 14.0f - 0.5f;
  float trip = 0.0f;
  if (tid < IMGD) {
    float xd = fabsf(cp - (float)tid) / 14.0f;
    trip = fmaxf(0.0f, 1.0f - xd);
  }
  red[tid] = trip;
  __syncthreads();
  for (int s = 128; s > 0; s >>= 1) {
    if (tid < s) red[tid] += red[tid + s];
    __syncthreads();
  }
  float Zp = red[0];
  __syncthreads();
  // A row q
  float cq = (q + 0.5f) * 14.0f - 0.5f;
  float triq = 0.0f;
  if (tid < IMGD) {
    float xd = fabsf(cq - (float)tid) / 14.0f;
    triq = fmaxf(0.0f, 1.0f - xd);
  }
  red[tid] = triq;
  __syncthreads();
  for (int s = 128; s > 0; s >>= 1) {
    if (tid < s) red[tid] += red[tid + s];
    __syncthreads();
  }
  float Zq = red[0];
  __syncthreads();

  int h0 = max(0, 14 * p - 7), h1 = min(IMGD - 1, 14 * p + 20);
  int w0 = max(0, 14 * q - 7), w1 = min(IMGD - 1, 14 * q + 20);
  int hl = h1 - h0 + 1, wl = w1 - w0 + 1;
  if (tid < hl) {
    float xd = fabsf(cp - (float)(h0 + tid)) / 14.0f;
    Apv[tid] = fmaxf(0.0f, 1.0f - xd) / Zp;   // same expr as build_A
  }
  if (tid < wl) {
    float xd = fabsf(cq - (float)(w0 + tid)) / 14.0f;
    Aqv[tid] = fmaxf(0.0f, 1.0f - xd) / Zq;
  }
  const float* cb = centers + (size_t)b * NK * 5;
  const float* c2b = c2g + (size_t)b * NK;
  if (tid < NK) {
    ck4[tid] = make_float4(cb[tid*5+0], cb[tid*5+1], cb[tid*5+2], cb[tid*5+3]);
    ck2[tid] = make_float2(cb[tid*5+4], c2b[tid]);
  }
  for (int t = tid; t < NK * 3; t += 256) sk[t] = 0.0f;
  if (tid < 4) candm[tid] = 0u;
  __syncthreads();

  // window-box pruning: UB = min_k(corner-max^2+3); keep iff clampdist^2<=UB+1
  const float ratio = ratio_f32();
  float f3mn = __fmul_rn((float)h0, ratio);
  float f3mx = __fmul_rn((float)h1, ratio);
  float f4mn = __fmul_rn((float)w0, ratio);
  float f4mx = __fmul_rn((float)w1, ratio);
  if (tid < 128) {
    float u = 3.4e38f;
    if (tid < NK) {
      float c3 = ck4[tid].w, c4 = ck2[tid].x;
      float dy = fmaxf(fabsf(c3 - f3mn), fabsf(c3 - f3mx));
      float dx = fmaxf(fabsf(c4 - f4mn), fabsf(c4 - f4mx));
      u = dy * dy + dx * dx + 3.0f;
    }
    ubk[tid] = u;
  }
  __syncthreads();
  for (int s = 64; s > 0; s >>= 1) {
    if (tid < s) ubk[tid] = fminf(ubk[tid], ubk[tid + s]);
    __syncthreads();
  }
  float lim = ubk[0] + 1.0f;
  if (tid < NK) {
    float c3 = ck4[tid].w, c4 = ck2[tid].x;
    float dy = fmaxf(0.0f, fmaxf(f3mn - c3, c3 - f3mx));
    float dx = fmaxf(0.0f, fmaxf(f4mn - c4, c4 - f4mx));
    if (dy * dy + dx * dx <= lim)
      atomicOr(&candm[tid >> 5], 1u << (tid & 31));
  }
  __syncthreads();
  if (tid == 0) {
    int len2 = 0;
    for (int w = 0; w < 4; ++w) {
      unsigned int m = candm[w];
      while (m) {
        int j = __ffs(m) - 1;
        m &= m - 1;
        clist[len2++] = (unsigned char)(w * 32 + j);
      }
    }
    clen = len2;
  }
  __syncthreads();

  const float* xb = x + (size_t)b * 3 * HW;
  int n = hl * wl;
  int ncand = clen;
  for (int r = 0; r < 4; ++r) {
    int idx = tid + r * 256;
    if (idx >= n) break;
    int dh = idx / wl;
    int hh = h0 + dh;
    int dw = idx - dh * wl;
    int ww = w0 + dw;
    int i = hh * IMGD + ww;
    float v0 = xb[i], v1 = xb[HW + i], v2 = xb[2 * HW + i];
    float f3 = __fmul_rn((float)hh, ratio);
    float f4 = __fmul_rn((float)ww, ratio);
    float fq = fsq5(v0, v1, v2, f3, f4);
    float bestd = 3.4e38f; int bk = 0;
    for (int j = 0; j < ncand; ++j) {   // ascending k: first-index ties safe
      int k = clist[j];
      float4 a4 = ck4[k];
      float2 a2 = ck2[k];
      float d = dist5s(v0, v1, v2, f3, f4, fq,
                       a4.x, a4.y, a4.z, a4.w, a2.x, a2.y);
      if (d < bestd) { bestd = d; bk = k; }
    }
    float wgt = Apv[dh] * Aqv[dw];
    atomicAdd(&sk[bk * 3 + 0], wgt * v0);
    atomicAdd(&sk[bk * 3 + 1], wgt * v1);
    atomicAdd(&sk[bk * 3 + 2], wgt * v2);
  }
  __syncthreads();

  float* outb = out + (size_t)b * OUT_PER_B;
  int base = p * 48 + q * 3;
  for (int t = tid; t < NK * 3; t += 256) {
    int k = t / 3, c = t - 3 * k;
    int f = k * 768 + base + c;           // flat [K,P,P,C] index
    outb[(f & 255) * 300 + (f >> 8)] = sk[t];  // view(B,300,256) + transpose
  }
}

extern "C" void kernel_launch(void* const* d_in, const int* in_sizes, int n_in,
                              void* d_out, int out_size, void* d_ws, size_t ws_size,
                              hipStream_t stream) {
  const float* x = (const float*)d_in[0];
  float* out = (float*)d_out;
  char* ws = (char*)d_ws;
  // ws layout:
  float* centers  = (float*)(ws + 16384);      // 16000 B
  float* c2g      = (float*)(ws + 49152);      // 3200 B
  float* partials = (float*)(ws + 1703936);    // 8*100*6*131*4 = 2515200 B

  dim3 cgrid(NCHUNK, NB);         // 131 x 8 — 1048 blocks
  iter_kernel<<<cgrid, 128, 0, stream>>>(x, centers, c2g, partials, 0);
  combine_update_kernel<<<NB * NK, 128, 0, stream>>>(centers, partials, c2g);
  for (int it = 1; it < 10; ++it) {
    iter_kernel<<<cgrid, 128, 0, stream>>>(x, centers, c2g, partials, 1);
    combine_update_kernel<<<NB * NK, 128, 0, stream>>>(centers, partials, c2g);
  }
  dim3 egrid(256, NB);            // (p*16+q) x b
  embed_kernel<<<egrid, 256, 0, stream>>>(x, centers, c2g, out);
}